// Round 1
// baseline (2569.263 us; speedup 1.0000x reference)
//
#include <hip/hip_runtime.h>
#include <hip/hip_bf16.h>
#include <math.h>

#define FEAT_IN 500
#define HID 64

// ---------------- degree count (over targets = col) ----------------
__global__ void deg_kernel(const int* __restrict__ col, int* __restrict__ deg, int E) {
    int e = blockIdx.x * blockDim.x + threadIdx.x;
    if (e < E) atomicAdd(&deg[col[e]], 1);
}

// ------------- single-block scan: ptr/cursor (exclusive), dinv -------------
__global__ void scan_kernel(const int* __restrict__ deg, int* __restrict__ ptr,
                            int* __restrict__ cursor, float* __restrict__ dinv, int n) {
    __shared__ int sdata[1024];
    __shared__ int s_running;
    const int tid = threadIdx.x;
    if (tid == 0) s_running = 0;
    __syncthreads();
    for (int base = 0; base < n; base += 1024) {
        int i = base + tid;
        int v = (i < n) ? deg[i] : 0;
        if (i < n) dinv[i] = rsqrtf((float)(v + 1));  // +1 self loop
        sdata[tid] = v;
        __syncthreads();
        for (int offd = 1; offd < 1024; offd <<= 1) {
            int t = (tid >= offd) ? sdata[tid - offd] : 0;
            __syncthreads();
            sdata[tid] += t;
            __syncthreads();
        }
        int incl = sdata[tid];
        int run = s_running;
        if (i < n) {
            int ex = run + incl - v;
            ptr[i] = ex;
            cursor[i] = ex;
        }
        __syncthreads();
        if (tid == 1023) s_running = run + sdata[1023];
        __syncthreads();
    }
    if (tid == 0) ptr[n] = s_running;
}

// ---------------- scatter edges into CSR (sorted by target) ----------------
__global__ void scatter_kernel(const int* __restrict__ row, const int* __restrict__ col,
                               const float* __restrict__ dinv, int* __restrict__ cursor,
                               int* __restrict__ csr_src, float* __restrict__ csr_w, int E) {
    int e = blockIdx.x * blockDim.x + threadIdx.x;
    if (e < E) {
        int c = col[e];
        int r = row[e];
        int p = atomicAdd(&cursor[c], 1);
        csr_src[p] = r;
        csr_w[p] = dinv[r] * dinv[c];
    }
}

// ------------- fused MLP: h=relu(xW1+b1); h2=hW2+b2; A=h2; out=temp[0]*h2 -------------
__global__ __launch_bounds__(256) void mlp_kernel(const float* __restrict__ x,
                                                  const float* __restrict__ W1,
                                                  const float* __restrict__ b1,
                                                  const float* __restrict__ W2,
                                                  const float* __restrict__ b2,
                                                  const float* __restrict__ temp,
                                                  float* __restrict__ A,
                                                  float* __restrict__ out, int n) {
    int wave = (blockIdx.x * blockDim.x + threadIdx.x) >> 6;
    int lane = threadIdx.x & 63;
    int r0 = wave * 4;
    if (r0 >= n) return;

    float acc1[4];
    float bb1 = b1[lane];
    acc1[0] = acc1[1] = acc1[2] = acc1[3] = bb1;

    const float* xr = x + (size_t)r0 * FEAT_IN;
    bool full = (r0 + 3 < n);
    if (full) {
        for (int k = 0; k < FEAT_IN; k += 4) {
            float4 xa = *(const float4*)(xr + k);
            float4 xb = *(const float4*)(xr + FEAT_IN + k);
            float4 xc = *(const float4*)(xr + 2 * FEAT_IN + k);
            float4 xd = *(const float4*)(xr + 3 * FEAT_IN + k);
            float w0 = W1[(k + 0) * HID + lane];
            float w1 = W1[(k + 1) * HID + lane];
            float w2 = W1[(k + 2) * HID + lane];
            float w3 = W1[(k + 3) * HID + lane];
            acc1[0] += xa.x * w0 + xa.y * w1 + xa.z * w2 + xa.w * w3;
            acc1[1] += xb.x * w0 + xb.y * w1 + xb.z * w2 + xb.w * w3;
            acc1[2] += xc.x * w0 + xc.y * w1 + xc.z * w2 + xc.w * w3;
            acc1[3] += xd.x * w0 + xd.y * w1 + xd.z * w2 + xd.w * w3;
        }
    } else {
        for (int r = 0; r < 4; r++) {
            if (r0 + r >= n) break;
            float a = bb1;
            const float* xrr = x + (size_t)(r0 + r) * FEAT_IN;
            for (int k = 0; k < FEAT_IN; k++) a += xrr[k] * W1[k * HID + lane];
            acc1[r] = a;
        }
    }
#pragma unroll
    for (int r = 0; r < 4; r++) acc1[r] = fmaxf(acc1[r], 0.0f);

    float acc2[4];
    float bb2 = b2[lane];
    acc2[0] = acc2[1] = acc2[2] = acc2[3] = bb2;
    for (int k = 0; k < HID; k++) {
        float w = W2[k * HID + lane];
        acc2[0] += __shfl(acc1[0], k) * w;
        acc2[1] += __shfl(acc1[1], k) * w;
        acc2[2] += __shfl(acc1[2], k) * w;
        acc2[3] += __shfl(acc1[3], k) * w;
    }
    float t0 = temp[0];
#pragma unroll
    for (int r = 0; r < 4; r++) {
        int i = r0 + r;
        if (i < n) {
            A[(size_t)i * HID + lane] = acc2[r];
            out[(size_t)i * HID + lane] = t0 * acc2[r];
        }
    }
}

// ------------- one propagation hop: nxt = Ahat*cur; out += temp[idx]*nxt -------------
__global__ __launch_bounds__(256) void hop_kernel(const int* __restrict__ ptr,
                                                  const int* __restrict__ csr_src,
                                                  const float* __restrict__ csr_w,
                                                  const float* __restrict__ dinv,
                                                  const float* __restrict__ cur,
                                                  float* __restrict__ nxt,
                                                  float* __restrict__ out,
                                                  const float* __restrict__ temp,
                                                  int tidx, int n) {
    int i = (blockIdx.x * blockDim.x + threadIdx.x) >> 6;
    int lane = threadIdx.x & 63;
    if (i >= n) return;

    float d = dinv[i];
    float acc = d * d * cur[(size_t)i * HID + lane];

    int s = ptr[i];
    int e = ptr[i + 1];
    int p = s;
    for (; p + 3 < e; p += 4) {
        int j0 = csr_src[p + 0];
        int j1 = csr_src[p + 1];
        int j2 = csr_src[p + 2];
        int j3 = csr_src[p + 3];
        float w0 = csr_w[p + 0];
        float w1 = csr_w[p + 1];
        float w2 = csr_w[p + 2];
        float w3 = csr_w[p + 3];
        float v0 = cur[(size_t)j0 * HID + lane];
        float v1 = cur[(size_t)j1 * HID + lane];
        float v2 = cur[(size_t)j2 * HID + lane];
        float v3 = cur[(size_t)j3 * HID + lane];
        acc += w0 * v0;
        acc += w1 * v1;
        acc += w2 * v2;
        acc += w3 * v3;
    }
    for (; p < e; p++) {
        int j = csr_src[p];
        acc += csr_w[p] * cur[(size_t)j * HID + lane];
    }

    float tk = temp[tidx];
    size_t o = (size_t)i * HID + lane;
    nxt[o] = acc;
    out[o] += tk * acc;
}

// ---------------- row log-softmax over 64 cols ----------------
__global__ __launch_bounds__(256) void lsm_kernel(float* __restrict__ out, int n) {
    int i = (blockIdx.x * blockDim.x + threadIdx.x) >> 6;
    int lane = threadIdx.x & 63;
    if (i >= n) return;
    size_t o = (size_t)i * HID + lane;
    float v = out[o];
    float m = v;
#pragma unroll
    for (int d = 32; d >= 1; d >>= 1) m = fmaxf(m, __shfl_xor(m, d));
    float ex = expf(v - m);
#pragma unroll
    for (int d = 32; d >= 1; d >>= 1) ex += __shfl_xor(ex, d);
    out[o] = v - m - logf(ex);
}

extern "C" void kernel_launch(void* const* d_in, const int* in_sizes, int n_in,
                              void* d_out, int out_size, void* d_ws, size_t ws_size,
                              hipStream_t stream) {
    const float* x    = (const float*)d_in[0];
    const int*   ei   = (const int*)d_in[1];
    const float* W1   = (const float*)d_in[2];
    const float* b1   = (const float*)d_in[3];
    const float* W2   = (const float*)d_in[4];
    const float* b2   = (const float*)d_in[5];
    const float* temp = (const float*)d_in[6];

    int n = in_sizes[0] / FEAT_IN;
    int E = in_sizes[1] / 2;
    int K = in_sizes[6] - 1;
    const int* row = ei;
    const int* col = ei + E;

    char* ws = (char*)d_ws;
    size_t off = 0;
    auto alloc = [&](size_t bytes) -> void* {
        void* p = (void*)(ws + off);
        off += (bytes + 255) & ~(size_t)255;
        return p;
    };
    size_t nf = (size_t)n * HID;
    float* A       = (float*)alloc(nf * sizeof(float));
    float* B       = (float*)alloc(nf * sizeof(float));
    float* dinv    = (float*)alloc((size_t)n * sizeof(float));
    int*   deg     = (int*)alloc((size_t)n * sizeof(int));
    int*   ptr     = (int*)alloc((size_t)(n + 1) * sizeof(int));
    int*   cursor  = (int*)alloc((size_t)n * sizeof(int));
    int*   csr_src = (int*)alloc((size_t)E * sizeof(int));
    float* csr_w   = (float*)alloc((size_t)E * sizeof(float));
    (void)ws_size;

    float* out = (float*)d_out;

    hipMemsetAsync(deg, 0, (size_t)n * sizeof(int), stream);

    int eb = (E + 255) / 256;
    deg_kernel<<<eb, 256, 0, stream>>>(col, deg, E);
    scan_kernel<<<1, 1024, 0, stream>>>(deg, ptr, cursor, dinv, n);
    scatter_kernel<<<eb, 256, 0, stream>>>(row, col, dinv, cursor, csr_src, csr_w, E);

    int mlp_waves = (n + 3) / 4;
    int mlp_blocks = (mlp_waves + 3) / 4;
    mlp_kernel<<<mlp_blocks, 256, 0, stream>>>(x, W1, b1, W2, b2, temp, A, out, n);

    int hop_blocks = (n + 3) / 4;
    float* cur = A;
    float* nxt = B;
    for (int k = 0; k < K; k++) {
        hop_kernel<<<hop_blocks, 256, 0, stream>>>(ptr, csr_src, csr_w, dinv, cur, nxt, out,
                                                   temp, k + 1, n);
        float* t = cur; cur = nxt; nxt = t;
    }

    lsm_kernel<<<hop_blocks, 256, 0, stream>>>(out, n);
}

// Round 2
// 2076.471 us; speedup vs baseline: 1.2373x; 1.2373x over previous
//
#include <hip/hip_runtime.h>
#include <hip/hip_bf16.h>
#include <math.h>

#define FEAT_IN 500
#define HID 64
#define MLP_ROWS 16
#define KC 100

// ---------------- degree count (over targets = col) ----------------
__global__ void deg_kernel(const int* __restrict__ col, int* __restrict__ deg, int E) {
    int e = blockIdx.x * blockDim.x + threadIdx.x;
    if (e < E) atomicAdd(&deg[col[e]], 1);
}

// ------------- shuffle-based scan: ptr/cursor (exclusive), dinv -------------
__global__ void scan_kernel(const int* __restrict__ deg, int* __restrict__ ptr,
                            int* __restrict__ cursor, float* __restrict__ dinv, int n) {
    __shared__ int wsum[16];
    __shared__ int s_running;
    const int tid = threadIdx.x;
    const int lane = tid & 63;
    const int wv = tid >> 6;
    if (tid == 0) s_running = 0;
    __syncthreads();
    for (int base = 0; base < n; base += 1024) {
        int i = base + tid;
        int v = (i < n) ? deg[i] : 0;
        if (i < n) dinv[i] = rsqrtf((float)(v + 1));  // +1 self loop
        // wave inclusive scan
        int sc = v;
#pragma unroll
        for (int d = 1; d < 64; d <<= 1) {
            int t = __shfl_up(sc, d);
            if (lane >= d) sc += t;
        }
        if (lane == 63) wsum[wv] = sc;
        __syncthreads();
        if (wv == 0) {
            int ws_ = (lane < 16) ? wsum[lane] : 0;
#pragma unroll
            for (int d = 1; d < 16; d <<= 1) {
                int t = __shfl_up(ws_, d);
                if (lane >= d) ws_ += t;
            }
            if (lane < 16) wsum[lane] = ws_;
        }
        __syncthreads();
        int wave_off = (wv == 0) ? 0 : wsum[wv - 1];
        int run = s_running;
        if (i < n) {
            int ex = run + wave_off + sc - v;
            ptr[i] = ex;
            cursor[i] = ex;
        }
        __syncthreads();
        if (tid == 0) s_running = run + wsum[15];
        __syncthreads();
    }
    if (tid == 0) ptr[n] = s_running;
}

// ---------------- scatter edges into CSR (sorted by target) ----------------
__global__ void scatter_kernel(const int* __restrict__ row, const int* __restrict__ col,
                               const float* __restrict__ dinv, int* __restrict__ cursor,
                               int* __restrict__ csr_src, float* __restrict__ csr_w, int E) {
    int e = blockIdx.x * blockDim.x + threadIdx.x;
    if (e < E) {
        int c = col[e];
        int r = row[e];
        int p = atomicAdd(&cursor[c], 1);
        csr_src[p] = r;
        csr_w[p] = dinv[r] * dinv[c];
    }
}

// ------------- fused MLP with LDS-staged x tile -------------
// block = 256 thr = 4 waves; 16 rows/block, 4 rows/wave, lane = out channel.
__global__ __launch_bounds__(256) void mlp_kernel(const float* __restrict__ x,
                                                  const float* __restrict__ W1,
                                                  const float* __restrict__ b1,
                                                  const float* __restrict__ W2,
                                                  const float* __restrict__ b2,
                                                  const float* __restrict__ temp,
                                                  float* __restrict__ A,
                                                  float* __restrict__ out, int n) {
    __shared__ float xs[MLP_ROWS][KC];   // 6.4 KB; KC*4=400B row stride, 16B aligned
    const int tid = threadIdx.x;
    const int lane = tid & 63;
    const int wv = tid >> 6;
    const int row0 = blockIdx.x * MLP_ROWS;
    const int wr = wv * 4;  // wave's first row within block

    float acc1[4] = {0.f, 0.f, 0.f, 0.f};

    for (int c = 0; c < FEAT_IN / KC; c++) {
        __syncthreads();  // xs reused: previous compute must be done
        // cooperative load: 16 rows x 100 floats = 400 float4
        for (int idx = tid; idx < (MLP_ROWS * KC) / 4; idx += 256) {
            int r = idx / 25;
            int cc = idx - r * 25;
            int gr = row0 + r;
            float4 v = {0.f, 0.f, 0.f, 0.f};
            if (gr < n) v = *(const float4*)(x + (size_t)gr * FEAT_IN + c * KC + cc * 4);
            *(float4*)&xs[r][cc * 4] = v;
        }
        __syncthreads();
        const float* w1p = W1 + (size_t)c * KC * HID + lane;
        for (int k4 = 0; k4 < KC / 4; k4++) {
            float4 xa = *(const float4*)&xs[wr + 0][k4 * 4];
            float4 xb = *(const float4*)&xs[wr + 1][k4 * 4];
            float4 xc = *(const float4*)&xs[wr + 2][k4 * 4];
            float4 xd = *(const float4*)&xs[wr + 3][k4 * 4];
            float w0 = w1p[(k4 * 4 + 0) * HID];
            float w1 = w1p[(k4 * 4 + 1) * HID];
            float w2 = w1p[(k4 * 4 + 2) * HID];
            float w3 = w1p[(k4 * 4 + 3) * HID];
            acc1[0] += xa.x * w0 + xa.y * w1 + xa.z * w2 + xa.w * w3;
            acc1[1] += xb.x * w0 + xb.y * w1 + xb.z * w2 + xb.w * w3;
            acc1[2] += xc.x * w0 + xc.y * w1 + xc.z * w2 + xc.w * w3;
            acc1[3] += xd.x * w0 + xd.y * w1 + xd.z * w2 + xd.w * w3;
        }
    }

    float bb1 = b1[lane];
#pragma unroll
    for (int r = 0; r < 4; r++) acc1[r] = fmaxf(acc1[r] + bb1, 0.0f);

    float acc2[4];
    float bb2 = b2[lane];
    acc2[0] = acc2[1] = acc2[2] = acc2[3] = bb2;
    for (int k = 0; k < HID; k++) {
        float w = W2[k * HID + lane];
        acc2[0] += __shfl(acc1[0], k) * w;
        acc2[1] += __shfl(acc1[1], k) * w;
        acc2[2] += __shfl(acc1[2], k) * w;
        acc2[3] += __shfl(acc1[3], k) * w;
    }
    float t0 = temp[0];
#pragma unroll
    for (int r = 0; r < 4; r++) {
        int i = row0 + wr + r;
        if (i < n) {
            A[(size_t)i * HID + lane] = acc2[r];
            out[(size_t)i * HID + lane] = t0 * acc2[r];
        }
    }
}

// ------------- one propagation hop: nxt = Ahat*cur; out += temp[idx]*nxt -------------
// 1 node/wave. lane = (edge subgroup g = lane>>4, feature quad q = (lane&15)*4).
// Each gather instruction pulls 4 edge rows x 256B = 1KB.
__global__ __launch_bounds__(256) void hop_kernel(const int* __restrict__ ptr,
                                                  const int* __restrict__ csr_src,
                                                  const float* __restrict__ csr_w,
                                                  const float* __restrict__ dinv,
                                                  const float* __restrict__ cur,
                                                  float* __restrict__ nxt,
                                                  float* __restrict__ out,
                                                  const float* __restrict__ temp,
                                                  int tidx, int n) {
    int i = (blockIdx.x * blockDim.x + threadIdx.x) >> 6;
    int lane = threadIdx.x & 63;
    if (i >= n) return;
    const int g = lane >> 4;
    const int q = (lane & 15) * 4;

    int s = ptr[i];
    int e = ptr[i + 1];
    float4 acc = {0.f, 0.f, 0.f, 0.f};
    float4 accB = {0.f, 0.f, 0.f, 0.f};

    int p = s;
    for (; p + 8 <= e; p += 8) {
        int j0 = csr_src[p + g];
        int j1 = csr_src[p + 4 + g];
        float w0 = csr_w[p + g];
        float w1 = csr_w[p + 4 + g];
        float4 v0 = *(const float4*)(cur + (size_t)j0 * HID + q);
        float4 v1 = *(const float4*)(cur + (size_t)j1 * HID + q);
        acc.x += w0 * v0.x; acc.y += w0 * v0.y; acc.z += w0 * v0.z; acc.w += w0 * v0.w;
        accB.x += w1 * v1.x; accB.y += w1 * v1.y; accB.z += w1 * v1.z; accB.w += w1 * v1.w;
    }
    for (; p < e; p += 4) {
        int pe = p + g;
        bool ok = pe < e;
        int pc = ok ? pe : (e - 1);
        int j = csr_src[pc];
        float w = ok ? csr_w[pc] : 0.0f;
        float4 v = *(const float4*)(cur + (size_t)j * HID + q);
        acc.x += w * v.x; acc.y += w * v.y; acc.z += w * v.z; acc.w += w * v.w;
    }
    acc.x += accB.x; acc.y += accB.y; acc.z += accB.z; acc.w += accB.w;

    // reduce across the 4 edge subgroups (lane bits 4,5)
#pragma unroll
    for (int m = 16; m <= 32; m <<= 1) {
        acc.x += __shfl_xor(acc.x, m);
        acc.y += __shfl_xor(acc.y, m);
        acc.z += __shfl_xor(acc.z, m);
        acc.w += __shfl_xor(acc.w, m);
    }

    float d = dinv[i];
    float dd = d * d;
    float4 self = *(const float4*)(cur + (size_t)i * HID + q);
    acc.x += dd * self.x; acc.y += dd * self.y; acc.z += dd * self.z; acc.w += dd * self.w;

    if (lane < 16) {
        float tk = temp[tidx];
        size_t o = (size_t)i * HID + q;
        *(float4*)(nxt + o) = acc;
        float4 ov = *(const float4*)(out + o);
        ov.x += tk * acc.x; ov.y += tk * acc.y; ov.z += tk * acc.z; ov.w += tk * acc.w;
        *(float4*)(out + o) = ov;
    }
}

// ---------------- row log-softmax over 64 cols ----------------
__global__ __launch_bounds__(256) void lsm_kernel(float* __restrict__ out, int n) {
    int i = (blockIdx.x * blockDim.x + threadIdx.x) >> 6;
    int lane = threadIdx.x & 63;
    if (i >= n) return;
    size_t o = (size_t)i * HID + lane;
    float v = out[o];
    float m = v;
#pragma unroll
    for (int d = 32; d >= 1; d >>= 1) m = fmaxf(m, __shfl_xor(m, d));
    float ex = expf(v - m);
#pragma unroll
    for (int d = 32; d >= 1; d >>= 1) ex += __shfl_xor(ex, d);
    out[o] = v - m - logf(ex);
}

extern "C" void kernel_launch(void* const* d_in, const int* in_sizes, int n_in,
                              void* d_out, int out_size, void* d_ws, size_t ws_size,
                              hipStream_t stream) {
    const float* x    = (const float*)d_in[0];
    const int*   ei   = (const int*)d_in[1];
    const float* W1   = (const float*)d_in[2];
    const float* b1   = (const float*)d_in[3];
    const float* W2   = (const float*)d_in[4];
    const float* b2   = (const float*)d_in[5];
    const float* temp = (const float*)d_in[6];

    int n = in_sizes[0] / FEAT_IN;
    int E = in_sizes[1] / 2;
    int K = in_sizes[6] - 1;
    const int* row = ei;
    const int* col = ei + E;

    char* ws = (char*)d_ws;
    size_t off = 0;
    auto alloc = [&](size_t bytes) -> void* {
        void* p = (void*)(ws + off);
        off += (bytes + 255) & ~(size_t)255;
        return p;
    };
    size_t nf = (size_t)n * HID;
    float* A       = (float*)alloc(nf * sizeof(float));
    float* B       = (float*)alloc(nf * sizeof(float));
    float* dinv    = (float*)alloc((size_t)n * sizeof(float));
    int*   deg     = (int*)alloc((size_t)n * sizeof(int));
    int*   ptr     = (int*)alloc((size_t)(n + 1) * sizeof(int));
    int*   cursor  = (int*)alloc((size_t)n * sizeof(int));
    int*   csr_src = (int*)alloc((size_t)E * sizeof(int));
    float* csr_w   = (float*)alloc((size_t)E * sizeof(float));
    (void)ws_size;

    float* out = (float*)d_out;

    hipMemsetAsync(deg, 0, (size_t)n * sizeof(int), stream);

    int eb = (E + 255) / 256;
    deg_kernel<<<eb, 256, 0, stream>>>(col, deg, E);
    scan_kernel<<<1, 1024, 0, stream>>>(deg, ptr, cursor, dinv, n);
    scatter_kernel<<<eb, 256, 0, stream>>>(row, col, dinv, cursor, csr_src, csr_w, E);

    int mlp_blocks = (n + MLP_ROWS - 1) / MLP_ROWS;
    mlp_kernel<<<mlp_blocks, 256, 0, stream>>>(x, W1, b1, W2, b2, temp, A, out, n);

    int hop_blocks = (n + 3) / 4;
    float* cur = A;
    float* nxt = B;
    for (int k = 0; k < K; k++) {
        hop_kernel<<<hop_blocks, 256, 0, stream>>>(ptr, csr_src, csr_w, dinv, cur, nxt, out,
                                                   temp, k + 1, n);
        float* t = cur; cur = nxt; nxt = t;
    }

    lsm_kernel<<<hop_blocks, 256, 0, stream>>>(out, n);
}

// Round 3
// 1560.197 us; speedup vs baseline: 1.6468x; 1.3309x over previous
//
#include <hip/hip_runtime.h>
#include <hip/hip_bf16.h>
#include <math.h>

#define FEAT_IN 500
#define HID 64
#define MLP_ROWS 16
#define KC 100

typedef unsigned int uint;
typedef unsigned short ushort;

__device__ inline ushort f2bf(float f) {
    uint u = __float_as_uint(f);
    uint r = (u + 0x7fff + ((u >> 16) & 1)) >> 16;
    return (ushort)r;
}

__device__ inline void bf8_unpack(const uint4 v, float f[8]) {
    uint a0 = v.x, a1 = v.y, a2 = v.z, a3 = v.w;
    f[0] = __uint_as_float(a0 << 16);
    f[1] = __uint_as_float(a0 & 0xffff0000u);
    f[2] = __uint_as_float(a1 << 16);
    f[3] = __uint_as_float(a1 & 0xffff0000u);
    f[4] = __uint_as_float(a2 << 16);
    f[5] = __uint_as_float(a2 & 0xffff0000u);
    f[6] = __uint_as_float(a3 << 16);
    f[7] = __uint_as_float(a3 & 0xffff0000u);
}

// ---------------- degree count (over targets = col) ----------------
__global__ void deg_kernel(const int* __restrict__ col, int* __restrict__ deg, int E) {
    int e = blockIdx.x * blockDim.x + threadIdx.x;
    if (e < E) atomicAdd(&deg[col[e]], 1);
}

// ------------- shuffle-based scan: ptr/cursor (exclusive), dinv -------------
__global__ void scan_kernel(const int* __restrict__ deg, int* __restrict__ ptr,
                            int* __restrict__ cursor, float* __restrict__ dinv, int n) {
    __shared__ int wsum[16];
    __shared__ int s_running;
    const int tid = threadIdx.x;
    const int lane = tid & 63;
    const int wv = tid >> 6;
    if (tid == 0) s_running = 0;
    __syncthreads();
    for (int base = 0; base < n; base += 1024) {
        int i = base + tid;
        int v = (i < n) ? deg[i] : 0;
        if (i < n) dinv[i] = rsqrtf((float)(v + 1));  // +1 self loop
        int sc = v;
#pragma unroll
        for (int d = 1; d < 64; d <<= 1) {
            int t = __shfl_up(sc, d);
            if (lane >= d) sc += t;
        }
        if (lane == 63) wsum[wv] = sc;
        __syncthreads();
        if (wv == 0) {
            int ws_ = (lane < 16) ? wsum[lane] : 0;
#pragma unroll
            for (int d = 1; d < 16; d <<= 1) {
                int t = __shfl_up(ws_, d);
                if (lane >= d) ws_ += t;
            }
            if (lane < 16) wsum[lane] = ws_;
        }
        __syncthreads();
        int wave_off = (wv == 0) ? 0 : wsum[wv - 1];
        int run = s_running;
        if (i < n) {
            int ex = run + wave_off + sc - v;
            ptr[i] = ex;
            cursor[i] = ex;
        }
        __syncthreads();
        if (tid == 0) s_running = run + wsum[15];
        __syncthreads();
    }
    if (tid == 0) ptr[n] = s_running;
}

// ---------------- scatter edges into CSR (sorted by target) ----------------
__global__ void scatter_kernel(const int* __restrict__ row, const int* __restrict__ col,
                               const float* __restrict__ dinv, int* __restrict__ cursor,
                               int* __restrict__ csr_src, float* __restrict__ csr_w, int E) {
    int e = blockIdx.x * blockDim.x + threadIdx.x;
    if (e < E) {
        int c = col[e];
        int r = row[e];
        int p = atomicAdd(&cursor[c], 1);
        csr_src[p] = r;
        csr_w[p] = dinv[r] * dinv[c];
    }
}

// ------------- fused MLP with LDS-staged x tile; A written as bf16 -------------
__global__ __launch_bounds__(256) void mlp_kernel(const float* __restrict__ x,
                                                  const float* __restrict__ W1,
                                                  const float* __restrict__ b1,
                                                  const float* __restrict__ W2,
                                                  const float* __restrict__ b2,
                                                  const float* __restrict__ temp,
                                                  ushort* __restrict__ A,
                                                  float* __restrict__ out, int n) {
    __shared__ float xs[MLP_ROWS][KC];
    const int tid = threadIdx.x;
    const int lane = tid & 63;
    const int wv = tid >> 6;
    const int row0 = blockIdx.x * MLP_ROWS;
    const int wr = wv * 4;

    float acc1[4] = {0.f, 0.f, 0.f, 0.f};

    for (int c = 0; c < FEAT_IN / KC; c++) {
        __syncthreads();
        for (int idx = tid; idx < (MLP_ROWS * KC) / 4; idx += 256) {
            int r = idx / 25;
            int cc = idx - r * 25;
            int gr = row0 + r;
            float4 v = {0.f, 0.f, 0.f, 0.f};
            if (gr < n) v = *(const float4*)(x + (size_t)gr * FEAT_IN + c * KC + cc * 4);
            *(float4*)&xs[r][cc * 4] = v;
        }
        __syncthreads();
        const float* w1p = W1 + (size_t)c * KC * HID + lane;
        for (int k4 = 0; k4 < KC / 4; k4++) {
            float4 xa = *(const float4*)&xs[wr + 0][k4 * 4];
            float4 xb = *(const float4*)&xs[wr + 1][k4 * 4];
            float4 xc = *(const float4*)&xs[wr + 2][k4 * 4];
            float4 xd = *(const float4*)&xs[wr + 3][k4 * 4];
            float w0 = w1p[(k4 * 4 + 0) * HID];
            float w1 = w1p[(k4 * 4 + 1) * HID];
            float w2 = w1p[(k4 * 4 + 2) * HID];
            float w3 = w1p[(k4 * 4 + 3) * HID];
            acc1[0] += xa.x * w0 + xa.y * w1 + xa.z * w2 + xa.w * w3;
            acc1[1] += xb.x * w0 + xb.y * w1 + xb.z * w2 + xb.w * w3;
            acc1[2] += xc.x * w0 + xc.y * w1 + xc.z * w2 + xc.w * w3;
            acc1[3] += xd.x * w0 + xd.y * w1 + xd.z * w2 + xd.w * w3;
        }
    }

    float bb1 = b1[lane];
#pragma unroll
    for (int r = 0; r < 4; r++) acc1[r] = fmaxf(acc1[r] + bb1, 0.0f);

    float acc2[4];
    float bb2 = b2[lane];
    acc2[0] = acc2[1] = acc2[2] = acc2[3] = bb2;
    for (int k = 0; k < HID; k++) {
        float w = W2[k * HID + lane];
        acc2[0] += __shfl(acc1[0], k) * w;
        acc2[1] += __shfl(acc1[1], k) * w;
        acc2[2] += __shfl(acc1[2], k) * w;
        acc2[3] += __shfl(acc1[3], k) * w;
    }
    float t0 = temp[0];
#pragma unroll
    for (int r = 0; r < 4; r++) {
        int i = row0 + wr + r;
        if (i < n) {
            A[(size_t)i * HID + lane] = f2bf(acc2[r]);
            out[(size_t)i * HID + lane] = t0 * acc2[r];
        }
    }
}

// ------------- one propagation hop, bf16 cur/nxt, fp32 accumulate -------------
// 1 node/wave. g = lane>>3 (edge slot, 8 per gather-instr), q = lane&7 (feature octet).
// Each gather instruction pulls 8 edge rows x 128B = 1KB.
__global__ __launch_bounds__(256) void hop_kernel(const int* __restrict__ ptr,
                                                  const int* __restrict__ csr_src,
                                                  const float* __restrict__ csr_w,
                                                  const float* __restrict__ dinv,
                                                  const ushort* __restrict__ cur,
                                                  ushort* __restrict__ nxt,
                                                  float* __restrict__ out,
                                                  const float* __restrict__ temp,
                                                  int tidx, int n) {
    int i = (blockIdx.x * blockDim.x + threadIdx.x) >> 6;
    int lane = threadIdx.x & 63;
    if (i >= n) return;
    const int g = lane >> 3;
    const int q = lane & 7;

    int s = ptr[i];
    int e = ptr[i + 1];
    const uint* curu = (const uint*)cur;  // 2 bf16 per uint; row = 32 uints

    float acc[8] = {0.f, 0.f, 0.f, 0.f, 0.f, 0.f, 0.f, 0.f};
    float accB[8] = {0.f, 0.f, 0.f, 0.f, 0.f, 0.f, 0.f, 0.f};

    int p = s;
    for (; p + 16 <= e; p += 16) {
        int j0 = csr_src[p + g];
        int j1 = csr_src[p + 8 + g];
        float w0 = csr_w[p + g];
        float w1 = csr_w[p + 8 + g];
        uint4 v0 = *(const uint4*)(curu + (size_t)j0 * 32 + q * 4);
        uint4 v1 = *(const uint4*)(curu + (size_t)j1 * 32 + q * 4);
        float f0[8], f1[8];
        bf8_unpack(v0, f0);
        bf8_unpack(v1, f1);
#pragma unroll
        for (int t = 0; t < 8; t++) acc[t] += w0 * f0[t];
#pragma unroll
        for (int t = 0; t < 8; t++) accB[t] += w1 * f1[t];
    }
    for (; p < e; p += 8) {
        int pe = p + g;
        bool ok = pe < e;
        int pc = ok ? pe : (e - 1);
        int j = csr_src[pc];
        float w = ok ? csr_w[pc] : 0.0f;
        uint4 v = *(const uint4*)(curu + (size_t)j * 32 + q * 4);
        float f[8];
        bf8_unpack(v, f);
#pragma unroll
        for (int t = 0; t < 8; t++) acc[t] += w * f[t];
    }
#pragma unroll
    for (int t = 0; t < 8; t++) acc[t] += accB[t];

    // reduce across the 8 edge subgroups (lane bits 3,4,5)
#pragma unroll
    for (int m = 8; m <= 32; m <<= 1) {
#pragma unroll
        for (int t = 0; t < 8; t++) acc[t] += __shfl_xor(acc[t], m);
    }

    // self loop
    float d = dinv[i];
    float dd = d * d;
    uint4 sv = *(const uint4*)(curu + (size_t)i * 32 + q * 4);
    float sf[8];
    bf8_unpack(sv, sf);
#pragma unroll
    for (int t = 0; t < 8; t++) acc[t] += dd * sf[t];

    if (lane < 8) {
        float tk = temp[tidx];
        // pack acc -> 8 bf16 -> uint4, store nxt
        uint4 pk;
        pk.x = (uint)f2bf(acc[0]) | ((uint)f2bf(acc[1]) << 16);
        pk.y = (uint)f2bf(acc[2]) | ((uint)f2bf(acc[3]) << 16);
        pk.z = (uint)f2bf(acc[4]) | ((uint)f2bf(acc[5]) << 16);
        pk.w = (uint)f2bf(acc[6]) | ((uint)f2bf(acc[7]) << 16);
        *(uint4*)((uint*)nxt + (size_t)i * 32 + q * 4) = pk;

        float* op = out + (size_t)i * HID + q * 8;
        float4 o0 = *(const float4*)(op);
        float4 o1 = *(const float4*)(op + 4);
        o0.x += tk * acc[0]; o0.y += tk * acc[1]; o0.z += tk * acc[2]; o0.w += tk * acc[3];
        o1.x += tk * acc[4]; o1.y += tk * acc[5]; o1.z += tk * acc[6]; o1.w += tk * acc[7];
        *(float4*)(op) = o0;
        *(float4*)(op + 4) = o1;
    }
}

// ---------------- row log-softmax over 64 cols ----------------
__global__ __launch_bounds__(256) void lsm_kernel(float* __restrict__ out, int n) {
    int i = (blockIdx.x * blockDim.x + threadIdx.x) >> 6;
    int lane = threadIdx.x & 63;
    if (i >= n) return;
    size_t o = (size_t)i * HID + lane;
    float v = out[o];
    float m = v;
#pragma unroll
    for (int d = 32; d >= 1; d >>= 1) m = fmaxf(m, __shfl_xor(m, d));
    float ex = expf(v - m);
#pragma unroll
    for (int d = 32; d >= 1; d >>= 1) ex += __shfl_xor(ex, d);
    out[o] = v - m - logf(ex);
}

extern "C" void kernel_launch(void* const* d_in, const int* in_sizes, int n_in,
                              void* d_out, int out_size, void* d_ws, size_t ws_size,
                              hipStream_t stream) {
    const float* x    = (const float*)d_in[0];
    const int*   ei   = (const int*)d_in[1];
    const float* W1   = (const float*)d_in[2];
    const float* b1   = (const float*)d_in[3];
    const float* W2   = (const float*)d_in[4];
    const float* b2   = (const float*)d_in[5];
    const float* temp = (const float*)d_in[6];

    int n = in_sizes[0] / FEAT_IN;
    int E = in_sizes[1] / 2;
    int K = in_sizes[6] - 1;
    const int* row = ei;
    const int* col = ei + E;

    char* ws = (char*)d_ws;
    size_t off = 0;
    auto alloc = [&](size_t bytes) -> void* {
        void* p = (void*)(ws + off);
        off += (bytes + 255) & ~(size_t)255;
        return p;
    };
    size_t nf = (size_t)n * HID;
    ushort* A      = (ushort*)alloc(nf * sizeof(ushort));
    ushort* B      = (ushort*)alloc(nf * sizeof(ushort));
    float* dinv    = (float*)alloc((size_t)n * sizeof(float));
    int*   deg     = (int*)alloc((size_t)n * sizeof(int));
    int*   ptr     = (int*)alloc((size_t)(n + 1) * sizeof(int));
    int*   cursor  = (int*)alloc((size_t)n * sizeof(int));
    int*   csr_src = (int*)alloc((size_t)E * sizeof(int));
    float* csr_w   = (float*)alloc((size_t)E * sizeof(float));
    (void)ws_size;

    float* out = (float*)d_out;

    hipMemsetAsync(deg, 0, (size_t)n * sizeof(int), stream);

    int eb = (E + 255) / 256;
    deg_kernel<<<eb, 256, 0, stream>>>(col, deg, E);
    scan_kernel<<<1, 1024, 0, stream>>>(deg, ptr, cursor, dinv, n);
    scatter_kernel<<<eb, 256, 0, stream>>>(row, col, dinv, cursor, csr_src, csr_w, E);

    int mlp_blocks = (n + MLP_ROWS - 1) / MLP_ROWS;
    mlp_kernel<<<mlp_blocks, 256, 0, stream>>>(x, W1, b1, W2, b2, temp, A, out, n);

    int hop_blocks = (n + 3) / 4;
    ushort* cur = A;
    ushort* nxt = B;
    for (int k = 0; k < K; k++) {
        hop_kernel<<<hop_blocks, 256, 0, stream>>>(ptr, csr_src, csr_w, dinv, cur, nxt, out,
                                                   temp, k + 1, n);
        ushort* t = cur; cur = nxt; nxt = t;
    }

    lsm_kernel<<<hop_blocks, 256, 0, stream>>>(out, n);
}

// Round 4
// 1438.851 us; speedup vs baseline: 1.7856x; 1.0843x over previous
//
#include <hip/hip_runtime.h>
#include <hip/hip_bf16.h>
#include <math.h>

#define FEAT_IN 500
#define HID 64
#define KPAD 512
#define NKC 16         // K chunks of 32 (512/32)
#define MT_PER_WAVE 2

typedef unsigned int uint;
typedef unsigned short ushort;
typedef __attribute__((ext_vector_type(8))) short bf16x8;
typedef __attribute__((ext_vector_type(4))) float f32x4;

__device__ inline ushort f2bf(float f) {
    uint u = __float_as_uint(f);
    uint r = (u + 0x7fff + ((u >> 16) & 1)) >> 16;
    return (ushort)r;
}

// pack two fp32 -> (bf16(a) | bf16(b)<<16), RNE
__device__ inline uint pk2(float a, float b) {
    uint ua = __float_as_uint(a), ub = __float_as_uint(b);
    ua = ua + 0x7fff + ((ua >> 16) & 1);
    ub = ub + 0x7fff + ((ub >> 16) & 1);
    return (ua >> 16) | (ub & 0xffff0000u);
}

__device__ inline void bf8_unpack(const uint4 v, float f[8]) {
    f[0] = __uint_as_float(v.x << 16);
    f[1] = __uint_as_float(v.x & 0xffff0000u);
    f[2] = __uint_as_float(v.y << 16);
    f[3] = __uint_as_float(v.y & 0xffff0000u);
    f[4] = __uint_as_float(v.z << 16);
    f[5] = __uint_as_float(v.z & 0xffff0000u);
    f[6] = __uint_as_float(v.w << 16);
    f[7] = __uint_as_float(v.w & 0xffff0000u);
}

// ---------------- degree count (over targets = col) ----------------
__global__ void deg_kernel(const int* __restrict__ col, int* __restrict__ deg, int E) {
    int e = blockIdx.x * blockDim.x + threadIdx.x;
    if (e < E) atomicAdd(&deg[col[e]], 1);
}

// ------------- shuffle-based scan: ptr/cursor (exclusive), dinv -------------
__global__ void scan_kernel(const int* __restrict__ deg, int* __restrict__ ptr,
                            int* __restrict__ cursor, float* __restrict__ dinv, int n) {
    __shared__ int wsum[16];
    __shared__ int s_running;
    const int tid = threadIdx.x;
    const int lane = tid & 63;
    const int wv = tid >> 6;
    if (tid == 0) s_running = 0;
    __syncthreads();
    for (int base = 0; base < n; base += 1024) {
        int i = base + tid;
        int v = (i < n) ? deg[i] : 0;
        if (i < n) dinv[i] = rsqrtf((float)(v + 1));  // +1 self loop
        int sc = v;
#pragma unroll
        for (int d = 1; d < 64; d <<= 1) {
            int t = __shfl_up(sc, d);
            if (lane >= d) sc += t;
        }
        if (lane == 63) wsum[wv] = sc;
        __syncthreads();
        if (wv == 0) {
            int ws_ = (lane < 16) ? wsum[lane] : 0;
#pragma unroll
            for (int d = 1; d < 16; d <<= 1) {
                int t = __shfl_up(ws_, d);
                if (lane >= d) ws_ += t;
            }
            if (lane < 16) wsum[lane] = ws_;
        }
        __syncthreads();
        int wave_off = (wv == 0) ? 0 : wsum[wv - 1];
        int run = s_running;
        if (i < n) {
            int ex = run + wave_off + sc - v;
            ptr[i] = ex;
            cursor[i] = ex;
        }
        __syncthreads();
        if (tid == 0) s_running = run + wsum[15];
        __syncthreads();
    }
    if (tid == 0) ptr[n] = s_running;
}

// ---------------- scatter edges into CSR (sorted by target) ----------------
__global__ void scatter_kernel(const int* __restrict__ row, const int* __restrict__ col,
                               const float* __restrict__ dinv, int* __restrict__ cursor,
                               int* __restrict__ csr_src, float* __restrict__ csr_w, int E) {
    int e = blockIdx.x * blockDim.x + threadIdx.x;
    if (e < E) {
        int c = col[e];
        int r = row[e];
        int p = atomicAdd(&cursor[c], 1);
        csr_src[p] = r;
        csr_w[p] = dinv[r] * dinv[c];
    }
}

// -------- swizzle W1 (500x64, pad K->512) and W2 (64x64) into MFMA B-frag order --------
// w1s[((c*4+t)*64 + lane)*8 + j] = bf16(W1[k][n]), k=c*32+(lane>>4)*8+j, n=t*16+(lane&15)
__global__ void swz_kernel(const float* __restrict__ W1, const float* __restrict__ W2,
                           ushort* __restrict__ w1s, ushort* __restrict__ w2s) {
    int idx = blockIdx.x * blockDim.x + threadIdx.x;  // [0, 36864)
    if (idx < 32768) {
        int j = idx & 7;
        int l = (idx >> 3) & 63;
        int t = (idx >> 9) & 3;
        int c = idx >> 11;
        int k = c * 32 + (l >> 4) * 8 + j;
        int nn = t * 16 + (l & 15);
        float v = (k < FEAT_IN) ? W1[(size_t)k * HID + nn] : 0.0f;
        w1s[idx] = f2bf(v);
    } else if (idx < 32768 + 4096) {
        int r = idx - 32768;
        int j = r & 7;
        int l = (r >> 3) & 63;
        int t = (r >> 9) & 3;
        int c = r >> 11;
        int k = c * 32 + (l >> 4) * 8 + j;
        int nn = t * 16 + (l & 15);
        w2s[r] = f2bf(W2[(size_t)k * HID + nn]);
    }
}

// ------------- MFMA MLP: h=relu(xW1+b1); h2=hW2+b2; A=bf16(h2); out=temp[0]*h2 -------------
// 4 waves/block; each wave handles MT_PER_WAVE M-tiles of 16 rows.
__global__ __launch_bounds__(256) void mlp_kernel(const float* __restrict__ x,
                                                  const ushort* __restrict__ w1s,
                                                  const float* __restrict__ b1,
                                                  const ushort* __restrict__ w2s,
                                                  const float* __restrict__ b2,
                                                  const float* __restrict__ temp,
                                                  ushort* __restrict__ A,
                                                  float* __restrict__ out, int n) {
    __shared__ ushort hls[4][16 * 72];  // per-wave h1 tile, row stride 72 bf16
    const int lane = threadIdx.x & 63;
    const int wv = threadIdx.x >> 6;
    const int g = lane >> 4;
    const int c15 = lane & 15;
    const int nmt = (n + 15) / 16;
    int mt0 = (blockIdx.x * 4 + wv) * MT_PER_WAVE;
    if (mt0 >= nmt) return;

    float b1v[4], b2v[4];
#pragma unroll
    for (int t = 0; t < 4; t++) {
        b1v[t] = b1[t * 16 + c15];
        b2v[t] = b2[t * 16 + c15];
    }
    float t0 = temp[0];
    ushort* hl = hls[wv];

    for (int m = 0; m < MT_PER_WAVE; m++) {
        int mt = mt0 + m;
        if (mt >= nmt) break;
        int row = mt * 16 + c15;
        const float* xr = x + (size_t)row * FEAT_IN;
        bool rok = (row < n);

        f32x4 acc[4] = {{0.f, 0.f, 0.f, 0.f}, {0.f, 0.f, 0.f, 0.f},
                        {0.f, 0.f, 0.f, 0.f}, {0.f, 0.f, 0.f, 0.f}};

        // full K chunks 0..14 (k = 0..479)
        for (int c = 0; c < 15; c++) {
            int k = c * 32 + g * 8;
            float4 lo = {0.f, 0.f, 0.f, 0.f}, hi = {0.f, 0.f, 0.f, 0.f};
            if (rok) {
                lo = *(const float4*)(xr + k);
                hi = *(const float4*)(xr + k + 4);
            }
            uint4 au;
            au.x = pk2(lo.x, lo.y);
            au.y = pk2(lo.z, lo.w);
            au.z = pk2(hi.x, hi.y);
            au.w = pk2(hi.z, hi.w);
            bf16x8 a = *(bf16x8*)&au;
            const ushort* wp = w1s + ((size_t)c * 4) * 512 + lane * 8;
#pragma unroll
            for (int t = 0; t < 4; t++) {
                bf16x8 b = *(const bf16x8*)(wp + t * 512);
                acc[t] = __builtin_amdgcn_mfma_f32_16x16x32_bf16(a, b, acc[t], 0, 0, 0);
            }
        }
        // tail chunk c=15 (k = 480..511, valid < 500)
        {
            float v[8];
#pragma unroll
            for (int j = 0; j < 8; j++) {
                int k = 480 + g * 8 + j;
                v[j] = (rok && k < FEAT_IN) ? xr[k] : 0.0f;
            }
            uint4 au;
            au.x = pk2(v[0], v[1]);
            au.y = pk2(v[2], v[3]);
            au.z = pk2(v[4], v[5]);
            au.w = pk2(v[6], v[7]);
            bf16x8 a = *(bf16x8*)&au;
            const ushort* wp = w1s + (size_t)15 * 4 * 512 + lane * 8;
#pragma unroll
            for (int t = 0; t < 4; t++) {
                bf16x8 b = *(const bf16x8*)(wp + t * 512);
                acc[t] = __builtin_amdgcn_mfma_f32_16x16x32_bf16(a, b, acc[t], 0, 0, 0);
            }
        }

        // h1 = relu(acc + b1) -> LDS (bf16, row stride 72)
#pragma unroll
        for (int t = 0; t < 4; t++) {
#pragma unroll
            for (int r = 0; r < 4; r++) {
                float h = fmaxf(acc[t][r] + b1v[t], 0.0f);
                hl[(g * 4 + r) * 72 + t * 16 + c15] = f2bf(h);
            }
        }

        // GEMM2: h1(16x64) @ W2(64x64)
        f32x4 acc2[4] = {{0.f, 0.f, 0.f, 0.f}, {0.f, 0.f, 0.f, 0.f},
                         {0.f, 0.f, 0.f, 0.f}, {0.f, 0.f, 0.f, 0.f}};
#pragma unroll
        for (int c2 = 0; c2 < 2; c2++) {
            bf16x8 a2 = *(const bf16x8*)(hl + c15 * 72 + c2 * 32 + g * 8);
            const ushort* wp2 = w2s + ((size_t)c2 * 4) * 512 + lane * 8;
#pragma unroll
            for (int t = 0; t < 4; t++) {
                bf16x8 b = *(const bf16x8*)(wp2 + t * 512);
                acc2[t] = __builtin_amdgcn_mfma_f32_16x16x32_bf16(a2, b, acc2[t], 0, 0, 0);
            }
        }

        // epilogue: A = bf16(h2); out = temp[0]*h2
#pragma unroll
        for (int t = 0; t < 4; t++) {
#pragma unroll
            for (int r = 0; r < 4; r++) {
                int orow = mt * 16 + g * 4 + r;
                if (orow < n) {
                    float d = acc2[t][r] + b2v[t];
                    size_t o = (size_t)orow * HID + t * 16 + c15;
                    A[o] = f2bf(d);
                    out[o] = t0 * d;
                }
            }
        }
    }
}

// ------------- one propagation hop, bf16 cur/nxt, fp32 accumulate -------------
__global__ __launch_bounds__(256) void hop_kernel(const int* __restrict__ ptr,
                                                  const int* __restrict__ csr_src,
                                                  const float* __restrict__ csr_w,
                                                  const float* __restrict__ dinv,
                                                  const ushort* __restrict__ cur,
                                                  ushort* __restrict__ nxt,
                                                  float* __restrict__ out,
                                                  const float* __restrict__ temp,
                                                  int tidx, int n) {
    int i = (blockIdx.x * blockDim.x + threadIdx.x) >> 6;
    int lane = threadIdx.x & 63;
    if (i >= n) return;
    const int g = lane >> 3;
    const int q = lane & 7;

    int s = ptr[i];
    int e = ptr[i + 1];
    const uint* curu = (const uint*)cur;

    float acc[8] = {0.f, 0.f, 0.f, 0.f, 0.f, 0.f, 0.f, 0.f};
    float accB[8] = {0.f, 0.f, 0.f, 0.f, 0.f, 0.f, 0.f, 0.f};

    int p = s;
    for (; p + 16 <= e; p += 16) {
        int j0 = csr_src[p + g];
        int j1 = csr_src[p + 8 + g];
        float w0 = csr_w[p + g];
        float w1 = csr_w[p + 8 + g];
        uint4 v0 = *(const uint4*)(curu + (size_t)j0 * 32 + q * 4);
        uint4 v1 = *(const uint4*)(curu + (size_t)j1 * 32 + q * 4);
        float f0[8], f1[8];
        bf8_unpack(v0, f0);
        bf8_unpack(v1, f1);
#pragma unroll
        for (int t = 0; t < 8; t++) acc[t] += w0 * f0[t];
#pragma unroll
        for (int t = 0; t < 8; t++) accB[t] += w1 * f1[t];
    }
    for (; p < e; p += 8) {
        int pe = p + g;
        bool ok = pe < e;
        int pc = ok ? pe : (e - 1);
        int j = csr_src[pc];
        float w = ok ? csr_w[pc] : 0.0f;
        uint4 v = *(const uint4*)(curu + (size_t)j * 32 + q * 4);
        float f[8];
        bf8_unpack(v, f);
#pragma unroll
        for (int t = 0; t < 8; t++) acc[t] += w * f[t];
    }
#pragma unroll
    for (int t = 0; t < 8; t++) acc[t] += accB[t];

#pragma unroll
    for (int m = 8; m <= 32; m <<= 1) {
#pragma unroll
        for (int t = 0; t < 8; t++) acc[t] += __shfl_xor(acc[t], m);
    }

    float d = dinv[i];
    float dd = d * d;
    uint4 sv = *(const uint4*)(curu + (size_t)i * 32 + q * 4);
    float sf[8];
    bf8_unpack(sv, sf);
#pragma unroll
    for (int t = 0; t < 8; t++) acc[t] += dd * sf[t];

    if (lane < 8) {
        float tk = temp[tidx];
        uint4 pk;
        pk.x = (uint)f2bf(acc[0]) | ((uint)f2bf(acc[1]) << 16);
        pk.y = (uint)f2bf(acc[2]) | ((uint)f2bf(acc[3]) << 16);
        pk.z = (uint)f2bf(acc[4]) | ((uint)f2bf(acc[5]) << 16);
        pk.w = (uint)f2bf(acc[6]) | ((uint)f2bf(acc[7]) << 16);
        *(uint4*)((uint*)nxt + (size_t)i * 32 + q * 4) = pk;

        float* op = out + (size_t)i * HID + q * 8;
        float4 o0 = *(const float4*)(op);
        float4 o1 = *(const float4*)(op + 4);
        o0.x += tk * acc[0]; o0.y += tk * acc[1]; o0.z += tk * acc[2]; o0.w += tk * acc[3];
        o1.x += tk * acc[4]; o1.y += tk * acc[5]; o1.z += tk * acc[6]; o1.w += tk * acc[7];
        *(float4*)(op) = o0;
        *(float4*)(op + 4) = o1;
    }
}

// ---------------- row log-softmax over 64 cols ----------------
__global__ __launch_bounds__(256) void lsm_kernel(float* __restrict__ out, int n) {
    int i = (blockIdx.x * blockDim.x + threadIdx.x) >> 6;
    int lane = threadIdx.x & 63;
    if (i >= n) return;
    size_t o = (size_t)i * HID + lane;
    float v = out[o];
    float m = v;
#pragma unroll
    for (int d = 32; d >= 1; d >>= 1) m = fmaxf(m, __shfl_xor(m, d));
    float ex = expf(v - m);
#pragma unroll
    for (int d = 32; d >= 1; d >>= 1) ex += __shfl_xor(ex, d);
    out[o] = v - m - logf(ex);
}

extern "C" void kernel_launch(void* const* d_in, const int* in_sizes, int n_in,
                              void* d_out, int out_size, void* d_ws, size_t ws_size,
                              hipStream_t stream) {
    const float* x    = (const float*)d_in[0];
    const int*   ei   = (const int*)d_in[1];
    const float* W1   = (const float*)d_in[2];
    const float* b1   = (const float*)d_in[3];
    const float* W2   = (const float*)d_in[4];
    const float* b2   = (const float*)d_in[5];
    const float* temp = (const float*)d_in[6];

    int n = in_sizes[0] / FEAT_IN;
    int E = in_sizes[1] / 2;
    int K = in_sizes[6] - 1;
    const int* row = ei;
    const int* col = ei + E;

    char* ws = (char*)d_ws;
    size_t off = 0;
    auto alloc = [&](size_t bytes) -> void* {
        void* p = (void*)(ws + off);
        off += (bytes + 255) & ~(size_t)255;
        return p;
    };
    size_t nf = (size_t)n * HID;
    ushort* A      = (ushort*)alloc(nf * sizeof(ushort));
    ushort* B      = (ushort*)alloc(nf * sizeof(ushort));
    float* dinv    = (float*)alloc((size_t)n * sizeof(float));
    int*   deg     = (int*)alloc((size_t)n * sizeof(int));
    int*   ptr     = (int*)alloc((size_t)(n + 1) * sizeof(int));
    int*   cursor  = (int*)alloc((size_t)n * sizeof(int));
    int*   csr_src = (int*)alloc((size_t)E * sizeof(int));
    float* csr_w   = (float*)alloc((size_t)E * sizeof(float));
    ushort* w1s    = (ushort*)alloc(32768 * sizeof(ushort));
    ushort* w2s    = (ushort*)alloc(4096 * sizeof(ushort));
    (void)ws_size;

    float* out = (float*)d_out;

    hipMemsetAsync(deg, 0, (size_t)n * sizeof(int), stream);

    int eb = (E + 255) / 256;
    deg_kernel<<<eb, 256, 0, stream>>>(col, deg, E);
    scan_kernel<<<1, 1024, 0, stream>>>(deg, ptr, cursor, dinv, n);
    scatter_kernel<<<eb, 256, 0, stream>>>(row, col, dinv, cursor, csr_src, csr_w, E);
    swz_kernel<<<(32768 + 4096 + 255) / 256, 256, 0, stream>>>(W1, W2, w1s, w2s);

    int nmt = (n + 15) / 16;
    int mlp_blocks = (nmt + 4 * MT_PER_WAVE - 1) / (4 * MT_PER_WAVE);
    mlp_kernel<<<mlp_blocks, 256, 0, stream>>>(x, w1s, b1, w2s, b2, temp, A, out, n);

    int hop_blocks = (n + 3) / 4;
    ushort* cur = A;
    ushort* nxt = B;
    for (int k = 0; k < K; k++) {
        hop_kernel<<<hop_blocks, 256, 0, stream>>>(ptr, csr_src, csr_w, dinv, cur, nxt, out,
                                                   temp, k + 1, n);
        ushort* t = cur; cur = nxt; nxt = t;
    }

    lsm_kernel<<<hop_blocks, 256, 0, stream>>>(out, n);
}